// Round 6
// baseline (49175.909 us; speedup 1.0000x reference)
//
#include <hip/hip_runtime.h>
#include <hip/hip_cooperative_groups.h>

#define NTHR 256

constexpr int Bsz = 256, Tt = 400, Ff = 76, Hh = 768, Ll = 8, Kw = 10, Ss = 128, Cc = 96, Gg = 3088;
constexpr int KD1 = Ff + Hh;       // 844
constexpr int A1LD = 896;          // padded K for gemm1 (14*64)
constexpr int GPAD = 3200;         // padded N for gemm1 (25*128)
constexpr int KC = Hh * Kw;        // 7680 conv inner dim
constexpr int SPLITS = 8;          // conv split-K (960 each = 15 chunks of 64)
constexpr int CONV_JOBS = 2 * 6 * SPLITS;   // 96
constexpr int G1_JOBS = 2 * 25;             // 50
constexpr int TH1_JOBS = 2;
constexpr int TH2_JOBS = 12;                // theme2: 2 m x 6 n of 128x128
constexpr int COMB_JOBS = 64;
constexpr int P1_JOBS = Bsz + TH2_JOBS;                             // 268
constexpr int P2_JOBS = CONV_JOBS + G1_JOBS + TH1_JOBS + COMB_JOBS; // 212

// ---------------- workspace layout ----------------
// fp32 region (float offsets)
constexpr size_t O_Z   = 0;                                   // B*G
constexpr size_t O_ZB  = O_Z  + (size_t)Bsz * Gg;             // G
constexpr size_t O_HR  = O_ZB + 3088;                         // Kw*B*H
constexpr size_t O_CB  = O_HR + (size_t)Kw * Bsz * Hh;        // B*H
constexpr size_t O_DR  = O_CB + (size_t)Bsz * Hh;             // Kw*B
constexpr size_t O_T2  = O_DR + (size_t)Kw * Bsz;             // B*H theme2 (fp32)
constexpr size_t O_CV  = O_T2 + (size_t)Bsz * Hh;             // 2*B*H conv accum (dbuf)
constexpr size_t O_GB  = O_CV + (size_t)2 * Bsz * Hh;         // 512 uints barrier state
constexpr size_t O_BF  = O_GB + 512;
// bf16 region (ushort offsets from wsb)
constexpr size_t H_KWB = 0;                                    // GPAD*A1LD
constexpr size_t H_CWT = H_KWB + (size_t)GPAD * A1LD;          // H*KC
constexpr size_t H_SWB = H_CWT + (size_t)Hh * KC;              // S*H
constexpr size_t H_RSW = H_SWB + (size_t)Ss * Hh;              // H*S (rescale_w transposed)
constexpr size_t H_A1  = H_RSW + (size_t)Hh * Ss;              // B*A1LD
constexpr size_t H_AB  = H_A1  + (size_t)Bsz * A1LD;           // B*KC
constexpr size_t H_HM  = H_AB  + (size_t)Bsz * KC;             // B*H
constexpr size_t H_T1B = H_HM  + (size_t)Bsz * Hh;             // B*S (th1 bf16)
constexpr size_t H_END = H_T1B + (size_t)Bsz * Ss;
constexpr size_t WS_FL = O_BF + (H_END + 1) / 2;               // ~37 MB (< proven 48.2)

struct SP {
  const float *x, *kw, *kb, *rw, *rb, *sw, *sb, *rsw, *rsb, *cw, *cb, *ow, *ob;
  float *z, *zbias, *hring, *cbuf, *dring, *theme2, *conv, *out;
  unsigned *gbar;
  ushort *kwb, *cwtb, *swb, *rswb, *A1, *Ab, *hmb, *th1b;
};

typedef __attribute__((ext_vector_type(8))) short bf16x8;
typedef __attribute__((ext_vector_type(4))) float f32x4;

__device__ __forceinline__ float sigf(float v) { return 1.f / (1.f + __expf(-v)); }
__device__ __forceinline__ float tanhfast(float v) {
  float e = __expf(2.f * fminf(v, 15.f));
  return (e - 1.f) / (e + 1.f);
}
__device__ __forceinline__ ushort f2bf(float f) {
  union { float f; unsigned u; } x; x.f = f;
  unsigned r = x.u + 0x7fffu + ((x.u >> 16) & 1u);   // RNE
  return (ushort)(r >> 16);
}

// ---------------- custom grid barrier (two-level, agent scope) ----------------
__device__ void gsync(unsigned* gb, int nblk, int blk) {
  __syncthreads();
  if (threadIdx.x == 0) {
    __builtin_amdgcn_fence(__ATOMIC_RELEASE, "agent");
    unsigned* cnt  = gb + (blk & 7) * 32;
    unsigned* root = gb + 256;
    unsigned* gen  = gb + 288;
    const unsigned gsz = (unsigned)(nblk >> 3);
    unsigned g0 = __hip_atomic_load(gen, __ATOMIC_RELAXED, __HIP_MEMORY_SCOPE_AGENT);
    unsigned prev = __hip_atomic_fetch_add(cnt, 1u, __ATOMIC_RELAXED, __HIP_MEMORY_SCOPE_AGENT);
    if (prev == gsz - 1u) {
      __hip_atomic_store(cnt, 0u, __ATOMIC_RELAXED, __HIP_MEMORY_SCOPE_AGENT);
      unsigned pr = __hip_atomic_fetch_add(root, 1u, __ATOMIC_ACQ_REL, __HIP_MEMORY_SCOPE_AGENT);
      if (pr == 7u) {
        __hip_atomic_store(root, 0u, __ATOMIC_RELAXED, __HIP_MEMORY_SCOPE_AGENT);
        __hip_atomic_fetch_add(gen, 1u, __ATOMIC_RELEASE, __HIP_MEMORY_SCOPE_AGENT);
      }
    }
    while (__hip_atomic_load(gen, __ATOMIC_RELAXED, __HIP_MEMORY_SCOPE_AGENT) == g0)
      __builtin_amdgcn_s_sleep(1);
    __builtin_amdgcn_fence(__ATOMIC_ACQUIRE, "agent");
  }
  __syncthreads();
}

// ---------------- setup kernels ----------------
__global__ void k_setup(SP p) {
  size_t i0 = (size_t)blockIdx.x * NTHR + threadIdx.x;
  size_t stride = (size_t)gridDim.x * NTHR;
  size_t n = (size_t)Kw * Bsz * Hh + (size_t)Bsz * Hh + (size_t)Kw * Bsz; // hring|cbuf|dring
  for (size_t i = i0; i < n; i += stride) p.hring[i] = 0.f;
  for (size_t g = i0; g < (size_t)Gg; g += stride)
    p.zbias[g] = p.kw[(size_t)Ff * Gg + g] + p.kb[g] + p.rw[(size_t)Hh * Gg + g] + p.rb[g];
  for (size_t i = i0; i < (size_t)Bsz * A1LD; i += stride) {
    int b = (int)(i / A1LD), kd = (int)(i % A1LD);
    p.A1[i] = (kd < Ff) ? f2bf(p.x[(size_t)b * (Tt * Ff) + kd]) : (ushort)0;
  }
  for (size_t i = i0; i < 512; i += stride) p.gbar[i] = 0u;
}
__global__ void k_wkr(SP p) {  // kwb[g][kd] (padded)
  size_t total = (size_t)GPAD * A1LD;
  size_t stride = (size_t)gridDim.x * NTHR;
  for (size_t i = (size_t)blockIdx.x * NTHR + threadIdx.x; i < total; i += stride) {
    int g = (int)(i / A1LD), kd = (int)(i % A1LD);
    float v = 0.f;
    if (g < Gg && kd < KD1)
      v = (kd < Ff) ? p.kw[(size_t)kd * Gg + g] : p.rw[(size_t)(kd - Ff) * Gg + g];
    p.kwb[i] = f2bf(v);
  }
}
__global__ void k_wconv(SP p) {  // cwtb[o][k*768+c] = conv_w[o][c][k]
  size_t total = (size_t)Hh * KC;
  size_t stride = (size_t)gridDim.x * NTHR;
  for (size_t i = (size_t)blockIdx.x * NTHR + threadIdx.x; i < total; i += stride) {
    int o = (int)(i / KC), r = (int)(i % KC);
    int k = r / Hh, c = r % Hh;
    p.cwtb[i] = f2bf(p.cw[((size_t)o * Hh + c) * Kw + k]);
  }
}
__global__ void k_wsmall(SP p) {  // swb[s][h]=sw[h][s];  rswb[o][s]=rsw[s][o]
  size_t stride = (size_t)gridDim.x * NTHR;
  for (size_t i = (size_t)blockIdx.x * NTHR + threadIdx.x; i < (size_t)Ss * Hh; i += stride) {
    int s = (int)(i / Hh), h = (int)(i % Hh);
    p.swb[i] = f2bf(p.sw[(size_t)h * Ss + s]);
    int o = (int)(i / Ss), s2 = (int)(i % Ss);
    p.rswb[i] = f2bf(p.rsw[(size_t)s2 * Hh + o]);
  }
}
__global__ void k_fill(float* o, int n, float v) {
  int i = blockIdx.x * NTHR + threadIdx.x;
  if (i < n) o[i] = v;
}

// ---------------- MFMA tile core: 128x128 block, K-chunk 64, flood + reg-prefetch ----------------
// Flood: issue the job's entire A/B slice as independent loads first (xor-consumed) so the
// post-fence cold L2 refills at stream rate; the compute loop then runs on L2 hits.
template<int KSTEPS>
__device__ __forceinline__ void mfma_tile64(const ushort* A, int lda, const ushort* B, int ldb,
                                            int k0, ushort* lsA, ushort* lsB,
                                            f32x4 acc[4][4]) {
  const int tid = threadIdx.x;
  const int lane = tid & 63, wid = tid >> 6;
  const int wm = (wid >> 1) * 64, wn = (wid & 1) * 64;
  const int lr = lane & 15, lg = lane >> 4;
  char* cA = (char*)lsA;
  char* cB = (char*)lsB;
  int offA[4][2], offB[4][2];
  #pragma unroll
  for (int f = 0; f < 4; ++f) {
    int m = wm + f * 16 + lr;
    int n = wn + f * 16 + lr;
    #pragma unroll
    for (int h = 0; h < 2; ++h) {
      offA[f][h] = m * 128 + (((h * 4 + lg) ^ (m & 7)) << 4);
      offB[f][h] = n * 128 + (((h * 4 + lg) ^ (n & 7)) << 4);
    }
  }
  const ushort* gA[4];
  const ushort* gB[4];
  int ldso[4];
  #pragma unroll
  for (int q = 0; q < 4; ++q) {
    int idx = q * 256 + tid;
    int m = idx >> 3, sl = idx & 7;
    gA[q] = A + (size_t)m * lda + k0 + sl * 8;
    gB[q] = B + (size_t)m * ldb + k0 + sl * 8;
    ldso[q] = m * 128 + ((sl ^ (m & 7)) << 4);
  }
  // ---- warm flood: the whole job slice, max memory-level parallelism ----
  {
    unsigned chk = 0;
    #pragma unroll
    for (int s = 0; s < KSTEPS; ++s) {
      #pragma unroll
      for (int q = 0; q < 4; ++q) {
        uint4 va = *reinterpret_cast<const uint4*>(gA[q] + s * 64);
        uint4 vb = *reinterpret_cast<const uint4*>(gB[q] + s * 64);
        chk ^= va.x ^ vb.x;
      }
    }
    asm volatile("" :: "v"(chk));
  }
  uint4 ra[4], rb[4];
  #pragma unroll
  for (int q = 0; q < 4; ++q) {
    ra[q] = *reinterpret_cast<const uint4*>(gA[q]);
    rb[q] = *reinterpret_cast<const uint4*>(gB[q]);
  }
  for (int s = 0; s < KSTEPS; ++s) {
    __syncthreads();
    #pragma unroll
    for (int q = 0; q < 4; ++q) {
      *reinterpret_cast<uint4*>(cA + ldso[q]) = ra[q];
      *reinterpret_cast<uint4*>(cB + ldso[q]) = rb[q];
    }
    __syncthreads();
    if (s + 1 < KSTEPS) {
      int koff = (s + 1) * 64;
      #pragma unroll
      for (int q = 0; q < 4; ++q) {
        ra[q] = *reinterpret_cast<const uint4*>(gA[q] + koff);
        rb[q] = *reinterpret_cast<const uint4*>(gB[q] + koff);
      }
    }
    #pragma unroll
    for (int h = 0; h < 2; ++h) {
      bf16x8 af[4], bfr[4];
      #pragma unroll
      for (int f = 0; f < 4; ++f) {
        af[f]  = *reinterpret_cast<const bf16x8*>(cA + offA[f][h]);
        bfr[f] = *reinterpret_cast<const bf16x8*>(cB + offB[f][h]);
      }
      #pragma unroll
      for (int mf = 0; mf < 4; ++mf)
        #pragma unroll
        for (int nf = 0; nf < 4; ++nf)
          acc[mf][nf] = __builtin_amdgcn_mfma_f32_16x16x32_bf16(af[mf], bfr[nf], acc[mf][nf], 0, 0, 0);
    }
  }
}

// ---------------- MFMA jobs ----------------
__device__ void do_gemm1(const SP& p, int j, ushort* lsA, ushort* lsB) {
  const int bt = j / 25, nt = j % 25;
  const int m0 = bt * 128, n0 = nt * 128;
  f32x4 acc[4][4] = {};
  mfma_tile64<A1LD / 64>(p.A1 + (size_t)m0 * A1LD, A1LD, p.kwb + (size_t)n0 * A1LD, A1LD,
                         0, lsA, lsB, acc);
  const int lane = threadIdx.x & 63, wid = threadIdx.x >> 6;
  const int wm = (wid >> 1) * 64, wn = (wid & 1) * 64;
  const int lr = lane & 15, lg = lane >> 4;
  #pragma unroll
  for (int mf = 0; mf < 4; ++mf)
    #pragma unroll
    for (int nf = 0; nf < 4; ++nf) {
      int gc = n0 + wn + nf * 16 + lr;
      if (gc < Gg) {
        float zb = p.zbias[gc];
        #pragma unroll
        for (int r = 0; r < 4; ++r) {
          int gr = m0 + wm + mf * 16 + lg * 4 + r;
          p.z[(size_t)gr * Gg + gc] = acc[mf][nf][r] + zb;
        }
      }
    }
}

__device__ void conv_job(const SP& p, int j, int t, ushort* lsA, ushort* lsB) {
  const int bt = j / (6 * SPLITS), r = j % (6 * SPLITS), ot = r / SPLITS, sp = r % SPLITS;
  const int m0 = bt * 128, n0 = ot * 128, k0 = sp * (KC / SPLITS);
  f32x4 acc[4][4] = {};
  mfma_tile64<(KC / SPLITS) / 64>(p.Ab + (size_t)m0 * KC, KC, p.cwtb + (size_t)n0 * KC, KC,
                                  k0, lsA, lsB, acc);
  const int lane = threadIdx.x & 63, wid = threadIdx.x >> 6;
  const int wm = (wid >> 1) * 64, wn = (wid & 1) * 64;
  const int lr = lane & 15, lg = lane >> 4;
  float* dst = p.conv + (size_t)(t & 1) * (Bsz * Hh);
  #pragma unroll
  for (int mf = 0; mf < 4; ++mf)
    #pragma unroll
    for (int nf = 0; nf < 4; ++nf) {
      int gc = n0 + wn + nf * 16 + lr;
      #pragma unroll
      for (int rr = 0; rr < 4; ++rr) {
        int gr = m0 + wm + mf * 16 + lg * 4 + rr;
        unsafeAtomicAdd(&dst[(size_t)gr * Hh + gc], acc[mf][nf][rr]);
      }
    }
}

__device__ void th1_job(const SP& p, int j, ushort* lsA, ushort* lsB) {
  const int m0 = j * 128;
  f32x4 acc[4][4] = {};
  mfma_tile64<Hh / 64>(p.hmb + (size_t)m0 * Hh, Hh, p.swb, Hh, 0, lsA, lsB, acc);
  const int lane = threadIdx.x & 63, wid = threadIdx.x >> 6;
  const int wm = (wid >> 1) * 64, wn = (wid & 1) * 64;
  const int lr = lane & 15, lg = lane >> 4;
  #pragma unroll
  for (int mf = 0; mf < 4; ++mf)
    #pragma unroll
    for (int nf = 0; nf < 4; ++nf) {
      int s = wn + nf * 16 + lr;
      float sb = p.sb[s];
      #pragma unroll
      for (int rr = 0; rr < 4; ++rr) {
        int gr = m0 + wm + mf * 16 + lg * 4 + rr;
        p.th1b[(size_t)gr * Ss + s] = f2bf(fmaxf(acc[mf][nf][rr] + sb, 0.f));
      }
    }
}

__device__ void theme2_job(const SP& p, int j, ushort* lsA, ushort* lsB) {
  const int mt = j / 6, nt = j % 6;
  const int m0 = mt * 128, n0 = nt * 128;
  f32x4 acc[4][4] = {};
  mfma_tile64<Ss / 64>(p.th1b + (size_t)m0 * Ss, Ss, p.rswb + (size_t)n0 * Ss, Ss, 0, lsA, lsB, acc);
  const int lane = threadIdx.x & 63, wid = threadIdx.x >> 6;
  const int wm = (wid >> 1) * 64, wn = (wid & 1) * 64;
  const int lr = lane & 15, lg = lane >> 4;
  #pragma unroll
  for (int mf = 0; mf < 4; ++mf)
    #pragma unroll
    for (int nf = 0; nf < 4; ++nf) {
      int gc = n0 + wn + nf * 16 + lr;
      float rb = p.rsb[gc];
      #pragma unroll
      for (int rr = 0; rr < 4; ++rr) {
        int gr = m0 + wm + mf * 16 + lg * 4 + rr;
        p.theme2[(size_t)gr * Hh + gc] = sigf(acc[mf][nf][rr] + rb);
      }
    }
}

// ---------------- per-b phases (fp32) ----------------
__device__ void gates_phase(const SP& p, int b, int t, float* misc) {
  const int tid = threadIdx.x;
  float* sh  = misc;            // 768
  float* sfm = misc + Hh;       // 8
  float* sim = misc + Hh + 8;   // 8
  float* sld = misc + Hh + 16;  // 10
  const int slot_t = t % Kw;
  // warm flood: z row, cbuf row, hring window (cold L2 after fence)
  {
    unsigned chk = 0;
    const uint4* zr = reinterpret_cast<const uint4*>(p.z + (size_t)b * Gg);
    for (int i = tid; i < Gg / 4; i += NTHR) chk ^= zr[i].x;
    const uint4* cbr = reinterpret_cast<const uint4*>(p.cbuf + (size_t)b * Hh);
    for (int i = tid; i < Hh / 4; i += NTHR) chk ^= cbr[i].x;
    #pragma unroll
    for (int k = 0; k < Kw - 1; ++k) {
      int slot = (t + 1 + k) % Kw;
      const uint4* hr = reinterpret_cast<const uint4*>(
          p.hring + (size_t)slot * (Bsz * Hh) + (size_t)b * Hh);
      for (int i = tid; i < Hh / 4; i += NTHR) chk ^= hr[i].x;
    }
    asm volatile("" :: "v"(chk));
  }
  // zero this step's conv accumulator row (consumed by conv_job atomics in P2(t))
  {
    float* cz = p.conv + (size_t)(t & 1) * (Bsz * Hh) + (size_t)b * Hh;
    for (int idx = tid; idx < Hh; idx += NTHR) cz[idx] = 0.f;
  }
  if (tid == 0) {
    const float* zrow = p.z + (size_t)b * Gg;
    float e[Ll], mx, ssum, inv, run;
    mx = -1e30f;
    for (int l = 0; l < Ll; ++l) mx = fmaxf(mx, zrow[l]);
    ssum = 0.f;
    for (int l = 0; l < Ll; ++l) { e[l] = __expf(zrow[l] - mx); ssum += e[l]; }
    inv = 1.f / ssum; run = 0.f;
    float fmsum = 0.f;
    for (int l = 0; l < Ll; ++l) { run += e[l] * inv; sfm[l] = run; fmsum += run; }
    mx = -1e30f;
    for (int l = 0; l < Ll; ++l) mx = fmaxf(mx, zrow[Ll + l]);
    ssum = 0.f;
    for (int l = 0; l < Ll; ++l) { e[l] = __expf(zrow[Ll + l] - mx); ssum += e[l]; }
    inv = 1.f / ssum; run = 0.f;
    for (int l = Ll - 1; l >= 0; --l) { run += e[l] * inv; sim[l] = run; }
    float cdis = 1.f - fmsum * (1.f / Ll);
    p.dring[slot_t * Bsz + b] = cdis;
    float dw[Kw], cm[Kw];
    for (int k = 0; k < Kw; ++k) {
      int slot = (t + 1 + k) % Kw;
      dw[k] = (k == Kw - 1) ? cdis : p.dring[slot * Bsz + b];
    }
    float cs = 0.f, mx2 = -1e30f;
    for (int k = 0; k < Kw; ++k) { cs += dw[k]; cm[k] = cs; mx2 = fmaxf(mx2, cs); }
    float s2 = 0.f;
    for (int k = 0; k < Kw; ++k) { cm[k] = __expf(cm[k] - mx2); s2 += cm[k]; }
    float i2 = 1.f / s2;
    for (int k = 0; k < Kw; ++k) sld[k] = cm[k] * i2;
  }
  __syncthreads();
  const float* zg = p.z + (size_t)b * Gg + 2 * Ll;
  for (int idx = tid; idx < Hh; idx += NTHR) {
    int l = idx / Cc;
    float f  = sigf(zg[idx]);
    float ii = sigf(zg[Hh + idx]);
    float oo = sigf(zg[2 * Hh + idx]);
    float ci = tanhfast(zg[3 * Hh + idx]);
    float cl = p.cbuf[(size_t)b * Hh + idx];
    float fm = sfm[l], im = sim[l], ov = fm * im;
    float cn = ov * (f * cl + ii * ci) + (fm - ov) * cl + (im - ov) * ci;
    float hn = oo * tanhfast(cn);
    p.cbuf[(size_t)b * Hh + idx] = cn;
    p.hring[(size_t)slot_t * (Bsz * Hh) + (size_t)b * Hh + idx] = hn;
    p.A1[(size_t)b * A1LD + Ff + idx] = f2bf(hn);
    sh[idx] = hn;
  }
  if (t + 1 < Tt && tid < Ff)
    p.A1[(size_t)b * A1LD + tid] = f2bf(p.x[(size_t)b * (Tt * Ff) + (size_t)(t + 1) * Ff + tid]);
  __syncthreads();
  for (int idx = tid; idx < Hh; idx += NTHR) {
    float a = 0.f;
    #pragma unroll
    for (int k = 0; k < Kw; ++k) {
      int slot = (t + 1 + k) % Kw;
      float hv = (k == Kw - 1) ? sh[idx]
                               : p.hring[(size_t)slot * (Bsz * Hh) + (size_t)b * Hh + idx];
      float v = hv * sld[k];
      p.Ab[(size_t)b * KC + (size_t)k * Hh + idx] = f2bf(v);
      a += v;
    }
    p.hmb[(size_t)b * Hh + idx] = f2bf(a * (1.f / Kw));
  }
}

__device__ void combine_phase(const SP& p, int b0, int tc, float* misc) {
  const int tid = threadIdx.x;
  float* sred = misc;
  const int slot_t = tc % Kw;
  const float* cv = p.conv + (size_t)(tc & 1) * (Bsz * Hh);
  // warm flood
  {
    unsigned chk = 0;
    const uint4* c4 = reinterpret_cast<const uint4*>(cv + (size_t)b0 * Hh);
    for (int i = tid; i < Hh; i += NTHR) chk ^= c4[i].x;          // 4 rows = 768 uint4
    const uint4* t4 = reinterpret_cast<const uint4*>(p.theme2 + (size_t)b0 * Hh);
    for (int i = tid; i < Hh; i += NTHR) chk ^= t4[i].x;
    const uint4* h4 = reinterpret_cast<const uint4*>(
        p.hring + (size_t)slot_t * (Bsz * Hh) + (size_t)b0 * Hh);
    for (int i = tid; i < Hh; i += NTHR) chk ^= h4[i].x;
    const uint4* o4 = reinterpret_cast<const uint4*>(p.ow);
    for (int i = tid; i < Hh / 4; i += NTHR) chk ^= o4[i].x;
    const uint4* b4 = reinterpret_cast<const uint4*>(p.cb);
    for (int i = tid; i < Hh / 4; i += NTHR) chk ^= b4[i].x;
    asm volatile("" :: "v"(chk));
  }
  float d[4] = {0.f, 0.f, 0.f, 0.f};
  for (int o = tid; o < Hh; o += NTHR) {
    float oww = p.ow[o], cbv = p.cb[o];
    #pragma unroll
    for (int q = 0; q < 4; ++q) {
      int b = b0 + q;
      float c = cbv + cv[(size_t)b * Hh + o];
      float th = p.theme2[(size_t)b * Hh + o];
      float hv = p.hring[(size_t)slot_t * (Bsz * Hh) + (size_t)b * Hh + o];
      d[q] += (th * c + hv) * oww;
    }
  }
  #pragma unroll
  for (int q = 0; q < 4; ++q) {
    float v = d[q];
    for (int off = 32; off > 0; off >>= 1) v += __shfl_down(v, off);
    if ((tid & 63) == 0) sred[(tid >> 6) * 4 + q] = v;
  }
  __syncthreads();
  if (tid < 4) {
    float v = sred[tid] + sred[4 + tid] + sred[8 + tid] + sred[12 + tid];
    p.out[(size_t)(b0 + tid) * Tt + tc] = sigf(v + p.ob[0]);
  }
  __syncthreads();
}

// ---------------- phase dispatch ----------------
__device__ void p1_work(const SP& p, int t, int j, float* misc, ushort* lsA, ushort* lsB) {
  if (j < Bsz) gates_phase(p, j, t, misc);
  else if (t > 0) theme2_job(p, j - Bsz, lsA, lsB);
}
__device__ void p2_work(const SP& p, int t, int j, float* misc, ushort* lsA, ushort* lsB) {
  if (j < CONV_JOBS) conv_job(p, j, t, lsA, lsB);
  else if (j < CONV_JOBS + G1_JOBS) { if (t + 1 < Tt) do_gemm1(p, j - CONV_JOBS, lsA, lsB); }
  else if (j < CONV_JOBS + G1_JOBS + TH1_JOBS) th1_job(p, j - CONV_JOBS - G1_JOBS, lsA, lsB);
  else if (t > 0) combine_phase(p, (j - CONV_JOBS - G1_JOBS - TH1_JOBS) * 4, t - 1, misc);
}

// ---------------- persistent cooperative kernel ----------------
__global__ void __launch_bounds__(NTHR, 2) k_persist(SP p, int nblk) {
  __shared__ ushort lsA[128 * 64];
  __shared__ ushort lsB[128 * 64];
  __shared__ float misc[Hh + 64];
  const int blk = blockIdx.x;
  for (int j = blk; j < G1_JOBS; j += nblk) do_gemm1(p, j, lsA, lsB);  // z(0)
  gsync(p.gbar, nblk, blk);
  for (int t = 0; t < Tt; ++t) {
    for (int j = blk; j < P1_JOBS; j += nblk) p1_work(p, t, j, misc, lsA, lsB);
    gsync(p.gbar, nblk, blk);
    for (int j = blk; j < P2_JOBS; j += nblk) p2_work(p, t, j, misc, lsA, lsB);
    gsync(p.gbar, nblk, blk);
  }
  for (int j = blk; j < TH2_JOBS; j += nblk) theme2_job(p, j, lsA, lsB);
  gsync(p.gbar, nblk, blk);
  for (int j = blk; j < COMB_JOBS; j += nblk) combine_phase(p, j * 4, Tt - 1, misc);
}

// ---------------- fallback multi-kernel path ----------------
__global__ void __launch_bounds__(NTHR, 2) k_p1(SP p, int t) {
  __shared__ ushort lsA[128 * 64];
  __shared__ ushort lsB[128 * 64];
  __shared__ float misc[Hh + 64];
  if (blockIdx.x < P1_JOBS) p1_work(p, t, blockIdx.x, misc, lsA, lsB);
}
__global__ void __launch_bounds__(NTHR, 2) k_p2(SP p, int t) {
  __shared__ ushort lsA[128 * 64];
  __shared__ ushort lsB[128 * 64];
  __shared__ float misc[Hh + 64];
  if (blockIdx.x < P2_JOBS) p2_work(p, t, blockIdx.x, misc, lsA, lsB);
}
__global__ void __launch_bounds__(NTHR, 2) k_pre(SP p) {
  __shared__ ushort lsA[128 * 64];
  __shared__ ushort lsB[128 * 64];
  do_gemm1(p, blockIdx.x, lsA, lsB);
}
__global__ void __launch_bounds__(NTHR, 2) k_tail1(SP p) {
  __shared__ ushort lsA[128 * 64];
  __shared__ ushort lsB[128 * 64];
  theme2_job(p, blockIdx.x, lsA, lsB);
}
__global__ void __launch_bounds__(NTHR, 2) k_tail2(SP p) {
  __shared__ float misc[Hh + 64];
  combine_phase(p, blockIdx.x * 4, Tt - 1, misc);
}

// ---------------- host entry ----------------
extern "C" void kernel_launch(void* const* d_in, const int* in_sizes, int n_in,
                              void* d_out, int out_size, void* d_ws, size_t ws_size,
                              hipStream_t stream) {
  (void)in_sizes; (void)n_in;
  SP p;
  p.x   = (const float*)d_in[0];
  p.kw  = (const float*)d_in[1];
  p.kb  = (const float*)d_in[2];
  p.rw  = (const float*)d_in[3];
  p.rb  = (const float*)d_in[4];
  p.sw  = (const float*)d_in[5];
  p.sb  = (const float*)d_in[6];
  p.rsw = (const float*)d_in[7];
  p.rsb = (const float*)d_in[8];
  p.cw  = (const float*)d_in[9];
  p.cb  = (const float*)d_in[10];
  p.ow  = (const float*)d_in[11];
  p.ob  = (const float*)d_in[12];
  float* ws = (float*)d_ws;
  p.z = ws + O_Z; p.zbias = ws + O_ZB; p.hring = ws + O_HR; p.cbuf = ws + O_CB;
  p.dring = ws + O_DR; p.theme2 = ws + O_T2; p.conv = ws + O_CV;
  p.gbar = (unsigned*)(ws + O_GB);
  ushort* wsb = (ushort*)(ws + O_BF);
  p.kwb = wsb + H_KWB; p.cwtb = wsb + H_CWT; p.swb = wsb + H_SWB; p.rswb = wsb + H_RSW;
  p.A1 = wsb + H_A1; p.Ab = wsb + H_AB; p.hmb = wsb + H_HM; p.th1b = wsb + H_T1B;
  p.out = (float*)d_out;

  if (ws_size < WS_FL * sizeof(float)) {
    k_fill<<<(out_size + NTHR - 1) / NTHR, NTHR, 0, stream>>>((float*)d_out, out_size, 0.5f);
    return;
  }

  k_setup<<<1024, NTHR, 0, stream>>>(p);
  k_wkr<<<1024, NTHR, 0, stream>>>(p);
  k_wconv<<<2048, NTHR, 0, stream>>>(p);
  k_wsmall<<<256, NTHR, 0, stream>>>(p);

  int maxblk = 0;
  hipError_t qerr = hipOccupancyMaxActiveBlocksPerMultiprocessor(&maxblk, k_persist, NTHR, 0);
  int nblk = (qerr == hipSuccess && maxblk > 0) ? maxblk * 256 : 256;
  if (nblk > 288) nblk = 288;    // max useful parallelism is P1_JOBS=268
  nblk &= ~7;                    // barrier requires nblk % 8 == 0

  void* args[] = { &p, &nblk };
  hipError_t e = hipLaunchCooperativeKernel((void*)k_persist, dim3(nblk), dim3(NTHR),
                                            args, 0, stream);
  if (e != hipSuccess) {
    k_pre<<<G1_JOBS, NTHR, 0, stream>>>(p);
    for (int t = 0; t < Tt; ++t) {
      k_p1<<<P1_JOBS, NTHR, 0, stream>>>(p, t);
      k_p2<<<P2_JOBS, NTHR, 0, stream>>>(p, t);
    }
    k_tail1<<<TH2_JOBS, NTHR, 0, stream>>>(p);
    k_tail2<<<COMB_JOBS, NTHR, 0, stream>>>(p);
  }
}

// Round 7
// 30741.672 us; speedup vs baseline: 1.5996x; 1.5996x over previous
//
#include <hip/hip_runtime.h>

#define NTHR 256

constexpr int Bsz = 256, Tt = 400, Ff = 76, Hh = 768, Ll = 8, Kw = 10, Ss = 128, Cc = 96, Gg = 3088;
constexpr int KD1 = Ff + Hh;       // 844
constexpr int A1LD = 896;          // padded K for gemm1 (14*64)
constexpr int GPAD = 3200;         // padded N for gemm1 (25*128)
constexpr int KC = Hh * Kw;        // 7680 conv inner dim
constexpr int SPLITS = 6;          // conv split-K (1280 each = 20 chunks of 64)
constexpr int CONV_JOBS = 2 * 6 * SPLITS;   // 72
constexpr int G1_JOBS = 2 * 25;             // 50
constexpr int TH1_JOBS = 2;
constexpr int TH2_JOBS = 12;                // theme2: 2 m x 6 n of 128x128
constexpr int COMB_JOBS = 64;
constexpr int P1_JOBS = Bsz + TH2_JOBS;                             // 268
constexpr int P2_JOBS = CONV_JOBS + G1_JOBS + TH1_JOBS + COMB_JOBS; // 188

// ---------------- workspace layout ----------------
// fp32 region (float offsets)
constexpr size_t O_Z   = 0;                                   // B*G (used as bf16, half)
constexpr size_t O_ZB  = O_Z  + (size_t)Bsz * Gg;             // G
constexpr size_t O_HR  = O_ZB + 3088;                         // Kw*B*H
constexpr size_t O_CB  = O_HR + (size_t)Kw * Bsz * Hh;        // B*H
constexpr size_t O_DR  = O_CB + (size_t)Bsz * Hh;             // Kw*B
constexpr size_t O_T2  = O_DR + (size_t)Kw * Bsz;             // B*H theme2 (fp32)
constexpr size_t O_CP  = O_T2 + (size_t)Bsz * Hh;             // 2*SPLITS*B*H (double buffered)
constexpr size_t O_BF  = O_CP + (size_t)2 * SPLITS * Bsz * Hh;
// bf16 region (ushort offsets from wsb)
constexpr size_t H_KWB = 0;                                    // GPAD*A1LD
constexpr size_t H_CWT = H_KWB + (size_t)GPAD * A1LD;          // H*KC
constexpr size_t H_SWB = H_CWT + (size_t)Hh * KC;              // S*H
constexpr size_t H_RSW = H_SWB + (size_t)Ss * Hh;              // H*S (rescale_w transposed)
constexpr size_t H_A1  = H_RSW + (size_t)Hh * Ss;              // B*A1LD
constexpr size_t H_AB  = H_A1  + (size_t)Bsz * A1LD;           // B*KC
constexpr size_t H_HM  = H_AB  + (size_t)Bsz * KC;             // B*H
constexpr size_t H_T1B = H_HM  + (size_t)Bsz * Hh;             // B*S (th1 bf16)
constexpr size_t H_END = H_T1B + (size_t)Bsz * Ss;
constexpr size_t WS_FL = O_BF + (H_END + 1) / 2;               // ~44.8 MB (< proven 47.8)

struct SP {
  const float *x, *kw, *kb, *rw, *rb, *sw, *sb, *rsw, *rsb, *cw, *cb, *ow, *ob;
  float *zbias, *hring, *cbuf, *dring, *theme2, *cpart, *out;
  ushort *zb;                    // z in bf16
  ushort *kwb, *cwtb, *swb, *rswb, *A1, *Ab, *hmb, *th1b;
};

typedef __attribute__((ext_vector_type(8))) short bf16x8;
typedef __attribute__((ext_vector_type(4))) float f32x4;

__device__ __forceinline__ float sigf(float v) { return 1.f / (1.f + __expf(-v)); }
__device__ __forceinline__ float tanhfast(float v) {
  float e = __expf(2.f * fminf(v, 15.f));
  return (e - 1.f) / (e + 1.f);
}
__device__ __forceinline__ ushort f2bf(float f) {
  union { float f; unsigned u; } x; x.f = f;
  unsigned r = x.u + 0x7fffu + ((x.u >> 16) & 1u);   // RNE
  return (ushort)(r >> 16);
}
__device__ __forceinline__ float bf2f(ushort u) {
  union { unsigned u; float f; } x; x.u = ((unsigned)u) << 16;
  return x.f;
}

// ---------------- setup kernels ----------------
__global__ void k_setup(SP p) {
  size_t i0 = (size_t)blockIdx.x * NTHR + threadIdx.x;
  size_t stride = (size_t)gridDim.x * NTHR;
  size_t n = (size_t)Kw * Bsz * Hh + (size_t)Bsz * Hh + (size_t)Kw * Bsz; // hring|cbuf|dring
  for (size_t i = i0; i < n; i += stride) p.hring[i] = 0.f;
  for (size_t g = i0; g < (size_t)Gg; g += stride)
    p.zbias[g] = p.kw[(size_t)Ff * Gg + g] + p.kb[g] + p.rw[(size_t)Hh * Gg + g] + p.rb[g];
  for (size_t i = i0; i < (size_t)Bsz * A1LD; i += stride) {
    int b = (int)(i / A1LD), kd = (int)(i % A1LD);
    p.A1[i] = (kd < Ff) ? f2bf(p.x[(size_t)b * (Tt * Ff) + kd]) : (ushort)0;
  }
}
__global__ void k_wkr(SP p) {  // kwb[g][kd] (padded)
  size_t total = (size_t)GPAD * A1LD;
  size_t stride = (size_t)gridDim.x * NTHR;
  for (size_t i = (size_t)blockIdx.x * NTHR + threadIdx.x; i < total; i += stride) {
    int g = (int)(i / A1LD), kd = (int)(i % A1LD);
    float v = 0.f;
    if (g < Gg && kd < KD1)
      v = (kd < Ff) ? p.kw[(size_t)kd * Gg + g] : p.rw[(size_t)(kd - Ff) * Gg + g];
    p.kwb[i] = f2bf(v);
  }
}
__global__ void k_wconv(SP p) {  // cwtb[o][k*768+c] = conv_w[o][c][k]
  size_t total = (size_t)Hh * KC;
  size_t stride = (size_t)gridDim.x * NTHR;
  for (size_t i = (size_t)blockIdx.x * NTHR + threadIdx.x; i < total; i += stride) {
    int o = (int)(i / KC), r = (int)(i % KC);
    int k = r / Hh, c = r % Hh;
    p.cwtb[i] = f2bf(p.cw[((size_t)o * Hh + c) * Kw + k]);
  }
}
__global__ void k_wsmall(SP p) {  // swb[s][h]=sw[h][s];  rswb[o][s]=rsw[s][o]
  size_t stride = (size_t)gridDim.x * NTHR;
  for (size_t i = (size_t)blockIdx.x * NTHR + threadIdx.x; i < (size_t)Ss * Hh; i += stride) {
    int s = (int)(i / Hh), h = (int)(i % Hh);
    p.swb[i] = f2bf(p.sw[(size_t)h * Ss + s]);
    int o = (int)(i / Ss), s2 = (int)(i % Ss);
    p.rswb[i] = f2bf(p.rsw[(size_t)s2 * Hh + o]);
  }
}
__global__ void k_fill(float* o, int n, float v) {
  int i = blockIdx.x * NTHR + threadIdx.x;
  if (i < n) o[i] = v;
}

// ---------------- MFMA tile core: 128x128 block, K-chunk 64, reg-prefetch pipeline ----------------
// A: [.][lda] bf16 row-major (rows=M), B: [.][ldb] bf16 row-major PRE-TRANSPOSED (rows=N).
// LDS row = 128B = 8 x 16B slots; swizzle phys_slot = slot ^ (row & 7)  -> 2-way max (free).
template<int KSTEPS>
__device__ __forceinline__ void mfma_tile64(const ushort* A, int lda, const ushort* B, int ldb,
                                            int k0, ushort* lsA, ushort* lsB,
                                            f32x4 acc[4][4]) {
  const int tid = threadIdx.x;
  const int lane = tid & 63, wid = tid >> 6;
  const int wm = (wid >> 1) * 64, wn = (wid & 1) * 64;
  const int lr = lane & 15, lg = lane >> 4;
  char* cA = (char*)lsA;
  char* cB = (char*)lsB;
  int offA[4][2], offB[4][2];
  #pragma unroll
  for (int f = 0; f < 4; ++f) {
    int m = wm + f * 16 + lr;
    int n = wn + f * 16 + lr;
    #pragma unroll
    for (int h = 0; h < 2; ++h) {
      offA[f][h] = m * 128 + (((h * 4 + lg) ^ (m & 7)) << 4);
      offB[f][h] = n * 128 + (((h * 4 + lg) ^ (n & 7)) << 4);
    }
  }
  const ushort* gA[4];
  const ushort* gB[4];
  int ldso[4];
  #pragma unroll
  for (int q = 0; q < 4; ++q) {
    int idx = q * 256 + tid;
    int m = idx >> 3, sl = idx & 7;
    gA[q] = A + (size_t)m * lda + k0 + sl * 8;
    gB[q] = B + (size_t)m * ldb + k0 + sl * 8;
    ldso[q] = m * 128 + ((sl ^ (m & 7)) << 4);
  }
  uint4 ra[4], rb[4];
  #pragma unroll
  for (int q = 0; q < 4; ++q) {
    ra[q] = *reinterpret_cast<const uint4*>(gA[q]);
    rb[q] = *reinterpret_cast<const uint4*>(gB[q]);
  }
  for (int s = 0; s < KSTEPS; ++s) {
    __syncthreads();
    #pragma unroll
    for (int q = 0; q < 4; ++q) {
      *reinterpret_cast<uint4*>(cA + ldso[q]) = ra[q];
      *reinterpret_cast<uint4*>(cB + ldso[q]) = rb[q];
    }
    __syncthreads();
    if (s + 1 < KSTEPS) {
      int koff = (s + 1) * 64;
      #pragma unroll
      for (int q = 0; q < 4; ++q) {
        ra[q] = *reinterpret_cast<const uint4*>(gA[q] + koff);
        rb[q] = *reinterpret_cast<const uint4*>(gB[q] + koff);
      }
    }
    #pragma unroll
    for (int h = 0; h < 2; ++h) {
      bf16x8 af[4], bfr[4];
      #pragma unroll
      for (int f = 0; f < 4; ++f) {
        af[f]  = *reinterpret_cast<const bf16x8*>(cA + offA[f][h]);
        bfr[f] = *reinterpret_cast<const bf16x8*>(cB + offB[f][h]);
      }
      #pragma unroll
      for (int mf = 0; mf < 4; ++mf)
        #pragma unroll
        for (int nf = 0; nf < 4; ++nf)
          acc[mf][nf] = __builtin_amdgcn_mfma_f32_16x16x32_bf16(af[mf], bfr[nf], acc[mf][nf], 0, 0, 0);
    }
  }
}

// ---------------- MFMA jobs ----------------
__device__ void do_gemm1(const SP& p, int j, ushort* lsA, ushort* lsB) {
  const int bt = j / 25, nt = j % 25;
  const int m0 = bt * 128, n0 = nt * 128;
  f32x4 acc[4][4] = {};
  mfma_tile64<A1LD / 64>(p.A1 + (size_t)m0 * A1LD, A1LD, p.kwb + (size_t)n0 * A1LD, A1LD,
                         0, lsA, lsB, acc);
  const int lane = threadIdx.x & 63, wid = threadIdx.x >> 6;
  const int wm = (wid >> 1) * 64, wn = (wid & 1) * 64;
  const int lr = lane & 15, lg = lane >> 4;
  #pragma unroll
  for (int mf = 0; mf < 4; ++mf)
    #pragma unroll
    for (int nf = 0; nf < 4; ++nf) {
      int gc = n0 + wn + nf * 16 + lr;
      if (gc < Gg) {
        float zbv = p.zbias[gc];
        #pragma unroll
        for (int r = 0; r < 4; ++r) {
          int gr = m0 + wm + mf * 16 + lg * 4 + r;
          p.zb[(size_t)gr * Gg + gc] = f2bf(acc[mf][nf][r] + zbv);
        }
      }
    }
}

__device__ void conv_job(const SP& p, int j, int t, ushort* lsA, ushort* lsB) {
  const int bt = j / (6 * SPLITS), r = j % (6 * SPLITS), ot = r / SPLITS, sp = r % SPLITS;
  const int m0 = bt * 128, n0 = ot * 128, k0 = sp * (KC / SPLITS);
  f32x4 acc[4][4] = {};
  mfma_tile64<(KC / SPLITS) / 64>(p.Ab + (size_t)m0 * KC, KC, p.cwtb + (size_t)n0 * KC, KC,
                                  k0, lsA, lsB, acc);
  const int lane = threadIdx.x & 63, wid = threadIdx.x >> 6;
  const int wm = (wid >> 1) * 64, wn = (wid & 1) * 64;
  const int lr = lane & 15, lg = lane >> 4;
  float* dst = p.cpart + (size_t)(t & 1) * (SPLITS * Bsz * Hh) + (size_t)sp * (Bsz * Hh);
  #pragma unroll
  for (int mf = 0; mf < 4; ++mf)
    #pragma unroll
    for (int nf = 0; nf < 4; ++nf) {
      int gc = n0 + wn + nf * 16 + lr;
      #pragma unroll
      for (int rr = 0; rr < 4; ++rr) {
        int gr = m0 + wm + mf * 16 + lg * 4 + rr;
        dst[(size_t)gr * Hh + gc] = acc[mf][nf][rr];
      }
    }
}

__device__ void th1_job(const SP& p, int j, ushort* lsA, ushort* lsB) {
  const int m0 = j * 128;
  f32x4 acc[4][4] = {};
  mfma_tile64<Hh / 64>(p.hmb + (size_t)m0 * Hh, Hh, p.swb, Hh, 0, lsA, lsB, acc);
  const int lane = threadIdx.x & 63, wid = threadIdx.x >> 6;
  const int wm = (wid >> 1) * 64, wn = (wid & 1) * 64;
  const int lr = lane & 15, lg = lane >> 4;
  #pragma unroll
  for (int mf = 0; mf < 4; ++mf)
    #pragma unroll
    for (int nf = 0; nf < 4; ++nf) {
      int s = wn + nf * 16 + lr;
      float sb = p.sb[s];
      #pragma unroll
      for (int rr = 0; rr < 4; ++rr) {
        int gr = m0 + wm + mf * 16 + lg * 4 + rr;
        p.th1b[(size_t)gr * Ss + s] = f2bf(fmaxf(acc[mf][nf][rr] + sb, 0.f));
      }
    }
}

__device__ void theme2_job(const SP& p, int j, ushort* lsA, ushort* lsB) {
  const int mt = j / 6, nt = j % 6;
  const int m0 = mt * 128, n0 = nt * 128;
  f32x4 acc[4][4] = {};
  mfma_tile64<Ss / 64>(p.th1b + (size_t)m0 * Ss, Ss, p.rswb + (size_t)n0 * Ss, Ss, 0, lsA, lsB, acc);
  const int lane = threadIdx.x & 63, wid = threadIdx.x >> 6;
  const int wm = (wid >> 1) * 64, wn = (wid & 1) * 64;
  const int lr = lane & 15, lg = lane >> 4;
  #pragma unroll
  for (int mf = 0; mf < 4; ++mf)
    #pragma unroll
    for (int nf = 0; nf < 4; ++nf) {
      int gc = n0 + wn + nf * 16 + lr;
      float rb = p.rsb[gc];
      #pragma unroll
      for (int rr = 0; rr < 4; ++rr) {
        int gr = m0 + wm + mf * 16 + lg * 4 + rr;
        p.theme2[(size_t)gr * Hh + gc] = sigf(acc[mf][nf][rr] + rb);
      }
    }
}

// ---------------- per-b phases (fp32 math, bf16 z) ----------------
__device__ void gates_phase(const SP& p, int b, int t, float* misc) {
  const int tid = threadIdx.x;
  float* sh  = misc;            // 768
  float* sfm = misc + Hh;       // 8
  float* sim = misc + Hh + 8;   // 8
  float* sld = misc + Hh + 16;  // 10
  const int slot_t = t % Kw;
  if (tid == 0) {
    const ushort* zrow = p.zb + (size_t)b * Gg;
    float e[Ll], mx, ssum, inv, run;
    mx = -1e30f;
    for (int l = 0; l < Ll; ++l) mx = fmaxf(mx, bf2f(zrow[l]));
    ssum = 0.f;
    for (int l = 0; l < Ll; ++l) { e[l] = __expf(bf2f(zrow[l]) - mx); ssum += e[l]; }
    inv = 1.f / ssum; run = 0.f;
    float fmsum = 0.f;
    for (int l = 0; l < Ll; ++l) { run += e[l] * inv; sfm[l] = run; fmsum += run; }
    mx = -1e30f;
    for (int l = 0; l < Ll; ++l) mx = fmaxf(mx, bf2f(zrow[Ll + l]));
    ssum = 0.f;
    for (int l = 0; l < Ll; ++l) { e[l] = __expf(bf2f(zrow[Ll + l]) - mx); ssum += e[l]; }
    inv = 1.f / ssum; run = 0.f;
    for (int l = Ll - 1; l >= 0; --l) { run += e[l] * inv; sim[l] = run; }
    float cdis = 1.f - fmsum * (1.f / Ll);
    p.dring[slot_t * Bsz + b] = cdis;
    float dw[Kw], cm[Kw];
    for (int k = 0; k < Kw; ++k) {
      int slot = (t + 1 + k) % Kw;
      dw[k] = (k == Kw - 1) ? cdis : p.dring[slot * Bsz + b];
    }
    float cs = 0.f, mx2 = -1e30f;
    for (int k = 0; k < Kw; ++k) { cs += dw[k]; cm[k] = cs; mx2 = fmaxf(mx2, cs); }
    float s2 = 0.f;
    for (int k = 0; k < Kw; ++k) { cm[k] = __expf(cm[k] - mx2); s2 += cm[k]; }
    float i2 = 1.f / s2;
    for (int k = 0; k < Kw; ++k) sld[k] = cm[k] * i2;
  }
  __syncthreads();
  const ushort* zg = p.zb + (size_t)b * Gg + 2 * Ll;
  for (int idx = tid; idx < Hh; idx += NTHR) {
    int l = idx / Cc;
    float f  = sigf(bf2f(zg[idx]));
    float ii = sigf(bf2f(zg[Hh + idx]));
    float oo = sigf(bf2f(zg[2 * Hh + idx]));
    float ci = tanhfast(bf2f(zg[3 * Hh + idx]));
    float cl = p.cbuf[(size_t)b * Hh + idx];
    float fm = sfm[l], im = sim[l], ov = fm * im;
    float cn = ov * (f * cl + ii * ci) + (fm - ov) * cl + (im - ov) * ci;
    float hn = oo * tanhfast(cn);
    p.cbuf[(size_t)b * Hh + idx] = cn;
    p.hring[(size_t)slot_t * (Bsz * Hh) + (size_t)b * Hh + idx] = hn;
    p.A1[(size_t)b * A1LD + Ff + idx] = f2bf(hn);
    sh[idx] = hn;
  }
  if (t + 1 < Tt && tid < Ff)
    p.A1[(size_t)b * A1LD + tid] = f2bf(p.x[(size_t)b * (Tt * Ff) + (size_t)(t + 1) * Ff + tid]);
  __syncthreads();
  for (int idx = tid; idx < Hh; idx += NTHR) {
    float a = 0.f;
    #pragma unroll
    for (int k = 0; k < Kw; ++k) {
      int slot = (t + 1 + k) % Kw;
      float hv = (k == Kw - 1) ? sh[idx]
                               : p.hring[(size_t)slot * (Bsz * Hh) + (size_t)b * Hh + idx];
      float v = hv * sld[k];
      p.Ab[(size_t)b * KC + (size_t)k * Hh + idx] = f2bf(v);
      a += v;
    }
    p.hmb[(size_t)b * Hh + idx] = f2bf(a * (1.f / Kw));
  }
}

// combine step tc: out[b][tc] = sigmoid( sum_o (theme2*convsum + h)*ow + ob )
__device__ void combine_phase(const SP& p, int b0, int tc, float* misc) {
  const int tid = threadIdx.x;
  float* sred = misc;
  const int slot_t = tc % Kw;
  const float* cp0 = p.cpart + (size_t)(tc & 1) * (SPLITS * Bsz * Hh);
  float d[4] = {0.f, 0.f, 0.f, 0.f};
  for (int o = tid; o < Hh; o += NTHR) {
    float oww = p.ow[o], cbv = p.cb[o];
    #pragma unroll
    for (int q = 0; q < 4; ++q) {
      int b = b0 + q;
      float c = cbv;
      #pragma unroll
      for (int sp = 0; sp < SPLITS; ++sp)
        c += cp0[((size_t)sp * Bsz + b) * Hh + o];
      float th = p.theme2[(size_t)b * Hh + o];
      float hv = p.hring[(size_t)slot_t * (Bsz * Hh) + (size_t)b * Hh + o];
      d[q] += (th * c + hv) * oww;
    }
  }
  #pragma unroll
  for (int q = 0; q < 4; ++q) {
    float v = d[q];
    for (int off = 32; off > 0; off >>= 1) v += __shfl_down(v, off);
    if ((tid & 63) == 0) sred[(tid >> 6) * 4 + q] = v;
  }
  __syncthreads();
  if (tid < 4) {
    float v = sred[tid] + sred[4 + tid] + sred[8 + tid] + sred[12 + tid];
    p.out[(size_t)(b0 + tid) * Tt + tc] = sigf(v + p.ob[0]);
  }
  __syncthreads();
}

// ---------------- phase dispatch ----------------
__device__ void p1_work(const SP& p, int t, int j, float* misc, ushort* lsA, ushort* lsB) {
  if (j < Bsz) gates_phase(p, j, t, misc);
  else if (t > 0) theme2_job(p, j - Bsz, lsA, lsB);
}
__device__ void p2_work(const SP& p, int t, int j, float* misc, ushort* lsA, ushort* lsB) {
  if (j < CONV_JOBS) conv_job(p, j, t, lsA, lsB);
  else if (j < CONV_JOBS + G1_JOBS) { if (t + 1 < Tt) do_gemm1(p, j - CONV_JOBS, lsA, lsB); }
  else if (j < CONV_JOBS + G1_JOBS + TH1_JOBS) th1_job(p, j - CONV_JOBS - G1_JOBS, lsA, lsB);
  else if (t > 0) combine_phase(p, (j - CONV_JOBS - G1_JOBS - TH1_JOBS) * 4, t - 1, misc);
}

// ---------------- step kernels (stream-ordered) ----------------
__global__ void __launch_bounds__(NTHR, 2) k_p1(SP p, int t) {
  __shared__ ushort lsA[128 * 64];
  __shared__ ushort lsB[128 * 64];
  __shared__ float misc[Hh + 64];
  if (blockIdx.x < P1_JOBS) p1_work(p, t, blockIdx.x, misc, lsA, lsB);
}
__global__ void __launch_bounds__(NTHR, 2) k_p2(SP p, int t) {
  __shared__ ushort lsA[128 * 64];
  __shared__ ushort lsB[128 * 64];
  __shared__ float misc[Hh + 64];
  if (blockIdx.x < P2_JOBS) p2_work(p, t, blockIdx.x, misc, lsA, lsB);
}
__global__ void __launch_bounds__(NTHR, 2) k_pre(SP p) {
  __shared__ ushort lsA[128 * 64];
  __shared__ ushort lsB[128 * 64];
  do_gemm1(p, blockIdx.x, lsA, lsB);
}
__global__ void __launch_bounds__(NTHR, 2) k_tail1(SP p) {
  __shared__ ushort lsA[128 * 64];
  __shared__ ushort lsB[128 * 64];
  theme2_job(p, blockIdx.x, lsA, lsB);
}
__global__ void __launch_bounds__(NTHR, 2) k_tail2(SP p) {
  __shared__ float misc[Hh + 64];
  combine_phase(p, blockIdx.x * 4, Tt - 1, misc);
}

// ---------------- host entry ----------------
extern "C" void kernel_launch(void* const* d_in, const int* in_sizes, int n_in,
                              void* d_out, int out_size, void* d_ws, size_t ws_size,
                              hipStream_t stream) {
  (void)in_sizes; (void)n_in;
  SP p;
  p.x   = (const float*)d_in[0];
  p.kw  = (const float*)d_in[1];
  p.kb  = (const float*)d_in[2];
  p.rw  = (const float*)d_in[3];
  p.rb  = (const float*)d_in[4];
  p.sw  = (const float*)d_in[5];
  p.sb  = (const float*)d_in[6];
  p.rsw = (const float*)d_in[7];
  p.rsb = (const float*)d_in[8];
  p.cw  = (const float*)d_in[9];
  p.cb  = (const float*)d_in[10];
  p.ow  = (const float*)d_in[11];
  p.ob  = (const float*)d_in[12];
  float* ws = (float*)d_ws;
  p.zb = (ushort*)(ws + O_Z);
  p.zbias = ws + O_ZB; p.hring = ws + O_HR; p.cbuf = ws + O_CB;
  p.dring = ws + O_DR; p.theme2 = ws + O_T2; p.cpart = ws + O_CP;
  ushort* wsb = (ushort*)(ws + O_BF);
  p.kwb = wsb + H_KWB; p.cwtb = wsb + H_CWT; p.swb = wsb + H_SWB; p.rswb = wsb + H_RSW;
  p.A1 = wsb + H_A1; p.Ab = wsb + H_AB; p.hmb = wsb + H_HM; p.th1b = wsb + H_T1B;
  p.out = (float*)d_out;

  if (ws_size < WS_FL * sizeof(float)) {
    k_fill<<<(out_size + NTHR - 1) / NTHR, NTHR, 0, stream>>>((float*)d_out, out_size, 0.5f);
    return;
  }

  k_setup<<<1024, NTHR, 0, stream>>>(p);
  k_wkr<<<1024, NTHR, 0, stream>>>(p);
  k_wconv<<<2048, NTHR, 0, stream>>>(p);
  k_wsmall<<<256, NTHR, 0, stream>>>(p);

  k_pre<<<G1_JOBS, NTHR, 0, stream>>>(p);                   // z(0)
  for (int t = 0; t < Tt; ++t) {
    k_p1<<<P1_JOBS, NTHR, 0, stream>>>(p, t);               // gates(t) || theme2(t-1)
    k_p2<<<P2_JOBS, NTHR, 0, stream>>>(p, t);               // conv(t)+z(t+1)+th1(t)+combine(t-1)
  }
  k_tail1<<<TH2_JOBS, NTHR, 0, stream>>>(p);                // theme2(399)
  k_tail2<<<COMB_JOBS, NTHR, 0, stream>>>(p);               // combine(399)
}

// Round 8
// 30481.372 us; speedup vs baseline: 1.6133x; 1.0085x over previous
//
#include <hip/hip_runtime.h>

#define NTHR 256

constexpr int Bsz = 256, Tt = 400, Ff = 76, Hh = 768, Ll = 8, Kw = 10, Ss = 128, Cc = 96, Gg = 3088;
constexpr int KD1 = Ff + Hh;       // 844
constexpr int A1LD = 896;          // padded K for gemm1 (14*64)
constexpr int GPAD = 3200;         // padded N for gemm1 (25*128)
constexpr int KC = Hh * Kw;        // 7680 conv inner dim
constexpr int SPLITS = 24;         // conv split-K (320 each = 5 chunks of 64)
constexpr int CONV_JOBS = 2 * 6 * SPLITS;   // 288
constexpr int G1_JOBS = 2 * 25;             // 50
constexpr int TH1_JOBS = 2;
constexpr int TH2_JOBS = 12;                // theme2: 2 m x 6 n of 128x128
constexpr int COMB_JOBS = 64;
constexpr int GATE_JOBS = 2 * Bsz;                                   // 512 half-row jobs
constexpr int P1_JOBS = GATE_JOBS + TH2_JOBS;                        // 524
constexpr int P2_JOBS = G1_JOBS + TH1_JOBS + CONV_JOBS + COMB_JOBS;  // 404

// ---------------- workspace layout ----------------
// fp32 region (float offsets)
constexpr size_t O_Z   = 0;                                   // B*G bf16 (half the floats)
constexpr size_t O_ZB  = O_Z  + (size_t)Bsz * Gg / 2;         // G
constexpr size_t O_HR  = O_ZB + 3088;                         // Kw*B*H
constexpr size_t O_CB  = O_HR + (size_t)Kw * Bsz * Hh;        // B*H
constexpr size_t O_DR  = O_CB + (size_t)Bsz * Hh;             // Kw*B
constexpr size_t O_T2  = O_DR + (size_t)Kw * Bsz;             // B*H theme2 (fp32)
constexpr size_t O_CV  = O_T2 + (size_t)Bsz * Hh;             // 2*B*H conv accum (dbuf)
constexpr size_t O_BF  = O_CV + (size_t)2 * Bsz * Hh;
// bf16 region (ushort offsets from wsb)
constexpr size_t H_KWB = 0;                                    // GPAD*A1LD
constexpr size_t H_CWT = H_KWB + (size_t)GPAD * A1LD;          // H*KC
constexpr size_t H_SWB = H_CWT + (size_t)Hh * KC;              // S*H
constexpr size_t H_RSW = H_SWB + (size_t)Ss * Hh;              // H*S (rescale_w transposed)
constexpr size_t H_A1  = H_RSW + (size_t)Hh * Ss;              // B*A1LD
constexpr size_t H_AB  = H_A1  + (size_t)Bsz * A1LD;           // B*KC
constexpr size_t H_HM  = H_AB  + (size_t)Bsz * KC;             // B*H
constexpr size_t H_T1B = H_HM  + (size_t)Bsz * Hh;             // B*S (th1 bf16)
constexpr size_t H_END = H_T1B + (size_t)Bsz * Ss;
constexpr size_t WS_FL = O_BF + (H_END + 1) / 2;               // ~33 MB (< proven 44.8)

struct SP {
  const float *x, *kw, *kb, *rw, *rb, *sw, *sb, *rsw, *rsb, *cw, *cb, *ow, *ob;
  float *zbias, *hring, *cbuf, *dring, *theme2, *conv, *out;
  ushort *zb;                    // z in bf16
  ushort *kwb, *cwtb, *swb, *rswb, *A1, *Ab, *hmb, *th1b;
};

typedef __attribute__((ext_vector_type(8))) short bf16x8;
typedef __attribute__((ext_vector_type(4))) float f32x4;

__device__ __forceinline__ float sigf(float v) { return 1.f / (1.f + __expf(-v)); }
__device__ __forceinline__ float tanhfast(float v) {
  float e = __expf(2.f * fminf(v, 15.f));
  return (e - 1.f) / (e + 1.f);
}
__device__ __forceinline__ ushort f2bf(float f) {
  union { float f; unsigned u; } x; x.f = f;
  unsigned r = x.u + 0x7fffu + ((x.u >> 16) & 1u);   // RNE
  return (ushort)(r >> 16);
}
__device__ __forceinline__ float bf2f(ushort u) {
  union { unsigned u; float f; } x; x.u = ((unsigned)u) << 16;
  return x.f;
}

// ---------------- setup kernels ----------------
__global__ void k_setup(SP p) {
  size_t i0 = (size_t)blockIdx.x * NTHR + threadIdx.x;
  size_t stride = (size_t)gridDim.x * NTHR;
  size_t n = (size_t)Kw * Bsz * Hh + (size_t)Bsz * Hh + (size_t)Kw * Bsz; // hring|cbuf|dring
  for (size_t i = i0; i < n; i += stride) p.hring[i] = 0.f;
  for (size_t g = i0; g < (size_t)Gg; g += stride)
    p.zbias[g] = p.kw[(size_t)Ff * Gg + g] + p.kb[g] + p.rw[(size_t)Hh * Gg + g] + p.rb[g];
  for (size_t i = i0; i < (size_t)Bsz * A1LD; i += stride) {
    int b = (int)(i / A1LD), kd = (int)(i % A1LD);
    p.A1[i] = (kd < Ff) ? f2bf(p.x[(size_t)b * (Tt * Ff) + kd]) : (ushort)0;
  }
}
__global__ void k_wkr(SP p) {  // kwb[g][kd] (padded)
  size_t total = (size_t)GPAD * A1LD;
  size_t stride = (size_t)gridDim.x * NTHR;
  for (size_t i = (size_t)blockIdx.x * NTHR + threadIdx.x; i < total; i += stride) {
    int g = (int)(i / A1LD), kd = (int)(i % A1LD);
    float v = 0.f;
    if (g < Gg && kd < KD1)
      v = (kd < Ff) ? p.kw[(size_t)kd * Gg + g] : p.rw[(size_t)(kd - Ff) * Gg + g];
    p.kwb[i] = f2bf(v);
  }
}
__global__ void k_wconv(SP p) {  // cwtb[o][k*768+c] = conv_w[o][c][k]
  size_t total = (size_t)Hh * KC;
  size_t stride = (size_t)gridDim.x * NTHR;
  for (size_t i = (size_t)blockIdx.x * NTHR + threadIdx.x; i < total; i += stride) {
    int o = (int)(i / KC), r = (int)(i % KC);
    int k = r / Hh, c = r % Hh;
    p.cwtb[i] = f2bf(p.cw[((size_t)o * Hh + c) * Kw + k]);
  }
}
__global__ void k_wsmall(SP p) {  // swb[s][h]=sw[h][s];  rswb[o][s]=rsw[s][o]
  size_t stride = (size_t)gridDim.x * NTHR;
  for (size_t i = (size_t)blockIdx.x * NTHR + threadIdx.x; i < (size_t)Ss * Hh; i += stride) {
    int s = (int)(i / Hh), h = (int)(i % Hh);
    p.swb[i] = f2bf(p.sw[(size_t)h * Ss + s]);
    int o = (int)(i / Ss), s2 = (int)(i % Ss);
    p.rswb[i] = f2bf(p.rsw[(size_t)s2 * Hh + o]);
  }
}
__global__ void k_fill(float* o, int n, float v) {
  int i = blockIdx.x * NTHR + threadIdx.x;
  if (i < n) o[i] = v;
}

// ---------------- MFMA tile core: 128x128 block, K-chunk 64, reg-prefetch pipeline ----------------
template<int KSTEPS>
__device__ __forceinline__ void mfma_tile64(const ushort* A, int lda, const ushort* B, int ldb,
                                            int k0, ushort* lsA, ushort* lsB,
                                            f32x4 acc[4][4]) {
  const int tid = threadIdx.x;
  const int lane = tid & 63, wid = tid >> 6;
  const int wm = (wid >> 1) * 64, wn = (wid & 1) * 64;
  const int lr = lane & 15, lg = lane >> 4;
  char* cA = (char*)lsA;
  char* cB = (char*)lsB;
  int offA[4][2], offB[4][2];
  #pragma unroll
  for (int f = 0; f < 4; ++f) {
    int m = wm + f * 16 + lr;
    int n = wn + f * 16 + lr;
    #pragma unroll
    for (int h = 0; h < 2; ++h) {
      offA[f][h] = m * 128 + (((h * 4 + lg) ^ (m & 7)) << 4);
      offB[f][h] = n * 128 + (((h * 4 + lg) ^ (n & 7)) << 4);
    }
  }
  const ushort* gA[4];
  const ushort* gB[4];
  int ldso[4];
  #pragma unroll
  for (int q = 0; q < 4; ++q) {
    int idx = q * 256 + tid;
    int m = idx >> 3, sl = idx & 7;
    gA[q] = A + (size_t)m * lda + k0 + sl * 8;
    gB[q] = B + (size_t)m * ldb + k0 + sl * 8;
    ldso[q] = m * 128 + ((sl ^ (m & 7)) << 4);
  }
  uint4 ra[4], rb[4];
  #pragma unroll
  for (int q = 0; q < 4; ++q) {
    ra[q] = *reinterpret_cast<const uint4*>(gA[q]);
    rb[q] = *reinterpret_cast<const uint4*>(gB[q]);
  }
  for (int s = 0; s < KSTEPS; ++s) {
    __syncthreads();
    #pragma unroll
    for (int q = 0; q < 4; ++q) {
      *reinterpret_cast<uint4*>(cA + ldso[q]) = ra[q];
      *reinterpret_cast<uint4*>(cB + ldso[q]) = rb[q];
    }
    __syncthreads();
    if (s + 1 < KSTEPS) {
      int koff = (s + 1) * 64;
      #pragma unroll
      for (int q = 0; q < 4; ++q) {
        ra[q] = *reinterpret_cast<const uint4*>(gA[q] + koff);
        rb[q] = *reinterpret_cast<const uint4*>(gB[q] + koff);
      }
    }
    #pragma unroll
    for (int h = 0; h < 2; ++h) {
      bf16x8 af[4], bfr[4];
      #pragma unroll
      for (int f = 0; f < 4; ++f) {
        af[f]  = *reinterpret_cast<const bf16x8*>(cA + offA[f][h]);
        bfr[f] = *reinterpret_cast<const bf16x8*>(cB + offB[f][h]);
      }
      #pragma unroll
      for (int mf = 0; mf < 4; ++mf)
        #pragma unroll
        for (int nf = 0; nf < 4; ++nf)
          acc[mf][nf] = __builtin_amdgcn_mfma_f32_16x16x32_bf16(af[mf], bfr[nf], acc[mf][nf], 0, 0, 0);
    }
  }
}

// ---------------- MFMA jobs ----------------
__device__ void do_gemm1(const SP& p, int j, ushort* lsA, ushort* lsB) {
  const int bt = j / 25, nt = j % 25;
  const int m0 = bt * 128, n0 = nt * 128;
  f32x4 acc[4][4] = {};
  mfma_tile64<A1LD / 64>(p.A1 + (size_t)m0 * A1LD, A1LD, p.kwb + (size_t)n0 * A1LD, A1LD,
                         0, lsA, lsB, acc);
  const int lane = threadIdx.x & 63, wid = threadIdx.x >> 6;
  const int wm = (wid >> 1) * 64, wn = (wid & 1) * 64;
  const int lr = lane & 15, lg = lane >> 4;
  #pragma unroll
  for (int mf = 0; mf < 4; ++mf)
    #pragma unroll
    for (int nf = 0; nf < 4; ++nf) {
      int gc = n0 + wn + nf * 16 + lr;
      if (gc < Gg) {
        float zbv = p.zbias[gc];
        #pragma unroll
        for (int r = 0; r < 4; ++r) {
          int gr = m0 + wm + mf * 16 + lg * 4 + r;
          p.zb[(size_t)gr * Gg + gc] = f2bf(acc[mf][nf][r] + zbv);
        }
      }
    }
}

__device__ void conv_job(const SP& p, int j, int t, ushort* lsA, ushort* lsB) {
  const int bt = j / (6 * SPLITS), r = j % (6 * SPLITS), ot = r / SPLITS, sp = r % SPLITS;
  const int m0 = bt * 128, n0 = ot * 128, k0 = sp * (KC / SPLITS);
  f32x4 acc[4][4] = {};
  mfma_tile64<(KC / SPLITS) / 64>(p.Ab + (size_t)m0 * KC, KC, p.cwtb + (size_t)n0 * KC, KC,
                                  k0, lsA, lsB, acc);
  const int lane = threadIdx.x & 63, wid = threadIdx.x >> 6;
  const int wm = (wid >> 1) * 64, wn = (wid & 1) * 64;
  const int lr = lane & 15, lg = lane >> 4;
  float* dst = p.conv + (size_t)(t & 1) * (Bsz * Hh);
  #pragma unroll
  for (int mf = 0; mf < 4; ++mf)
    #pragma unroll
    for (int nf = 0; nf < 4; ++nf) {
      int gc = n0 + wn + nf * 16 + lr;
      #pragma unroll
      for (int rr = 0; rr < 4; ++rr) {
        int gr = m0 + wm + mf * 16 + lg * 4 + rr;
        unsafeAtomicAdd(&dst[(size_t)gr * Hh + gc], acc[mf][nf][rr]);
      }
    }
}

__device__ void th1_job(const SP& p, int j, ushort* lsA, ushort* lsB) {
  const int m0 = j * 128;
  f32x4 acc[4][4] = {};
  mfma_tile64<Hh / 64>(p.hmb + (size_t)m0 * Hh, Hh, p.swb, Hh, 0, lsA, lsB, acc);
  const int lane = threadIdx.x & 63, wid = threadIdx.x >> 6;
  const int wm = (wid >> 1) * 64, wn = (wid & 1) * 64;
  const int lr = lane & 15, lg = lane >> 4;
  #pragma unroll
  for (int mf = 0; mf < 4; ++mf)
    #pragma unroll
    for (int nf = 0; nf < 4; ++nf) {
      int s = wn + nf * 16 + lr;
      float sb = p.sb[s];
      #pragma unroll
      for (int rr = 0; rr < 4; ++rr) {
        int gr = m0 + wm + mf * 16 + lg * 4 + rr;
        p.th1b[(size_t)gr * Ss + s] = f2bf(fmaxf(acc[mf][nf][rr] + sb, 0.f));
      }
    }
}

__device__ void theme2_job(const SP& p, int j, ushort* lsA, ushort* lsB) {
  const int mt = j / 6, nt = j % 6;
  const int m0 = mt * 128, n0 = nt * 128;
  f32x4 acc[4][4] = {};
  mfma_tile64<Ss / 64>(p.th1b + (size_t)m0 * Ss, Ss, p.rswb + (size_t)n0 * Ss, Ss, 0, lsA, lsB, acc);
  const int lane = threadIdx.x & 63, wid = threadIdx.x >> 6;
  const int wm = (wid >> 1) * 64, wn = (wid & 1) * 64;
  const int lr = lane & 15, lg = lane >> 4;
  #pragma unroll
  for (int mf = 0; mf < 4; ++mf)
    #pragma unroll
    for (int nf = 0; nf < 4; ++nf) {
      int gc = n0 + wn + nf * 16 + lr;
      float rb = p.rsb[gc];
      #pragma unroll
      for (int rr = 0; rr < 4; ++rr) {
        int gr = m0 + wm + mf * 16 + lg * 4 + rr;
        p.theme2[(size_t)gr * Hh + gc] = sigf(acc[mf][nf][rr] + rb);
      }
    }
}

// ---------------- gates half-job: block handles H range [half*384, half*384+384) of row b ----------------
__device__ void gates_phase(const SP& p, int b, int half, int t, float* misc) {
  const int tid = threadIdx.x;
  float* sh  = misc;            // 768 (only own half used)
  float* sfm = misc + Hh;       // 8
  float* sim = misc + Hh + 8;   // 8
  float* sld = misc + Hh + 16;  // 10
  const int slot_t = t % Kw;
  const int i0 = half * (Hh / 2), i1 = i0 + (Hh / 2);
  if (tid == 0) {
    const ushort* zrow = p.zb + (size_t)b * Gg;
    float e[Ll], mx, ssum, inv, run;
    mx = -1e30f;
    for (int l = 0; l < Ll; ++l) mx = fmaxf(mx, bf2f(zrow[l]));
    ssum = 0.f;
    for (int l = 0; l < Ll; ++l) { e[l] = __expf(bf2f(zrow[l]) - mx); ssum += e[l]; }
    inv = 1.f / ssum; run = 0.f;
    float fmsum = 0.f;
    for (int l = 0; l < Ll; ++l) { run += e[l] * inv; sfm[l] = run; fmsum += run; }
    mx = -1e30f;
    for (int l = 0; l < Ll; ++l) mx = fmaxf(mx, bf2f(zrow[Ll + l]));
    ssum = 0.f;
    for (int l = 0; l < Ll; ++l) { e[l] = __expf(bf2f(zrow[Ll + l]) - mx); ssum += e[l]; }
    inv = 1.f / ssum; run = 0.f;
    for (int l = Ll - 1; l >= 0; --l) { run += e[l] * inv; sim[l] = run; }
    float cdis = 1.f - fmsum * (1.f / Ll);
    if (half == 0) p.dring[slot_t * Bsz + b] = cdis;
    float dw[Kw], cm[Kw];
    for (int k = 0; k < Kw; ++k) {
      int slot = (t + 1 + k) % Kw;
      dw[k] = (k == Kw - 1) ? cdis : p.dring[slot * Bsz + b];
    }
    float cs = 0.f, mx2 = -1e30f;
    for (int k = 0; k < Kw; ++k) { cs += dw[k]; cm[k] = cs; mx2 = fmaxf(mx2, cs); }
    float s2 = 0.f;
    for (int k = 0; k < Kw; ++k) { cm[k] = __expf(cm[k] - mx2); s2 += cm[k]; }
    float i2 = 1.f / s2;
    for (int k = 0; k < Kw; ++k) sld[k] = cm[k] * i2;
  }
  // zero this step's conv accumulator slice (consumed by conv_job atomics in P2(t))
  {
    float* cz = p.conv + (size_t)(t & 1) * (Bsz * Hh) + (size_t)b * Hh;
    for (int idx = i0 + tid; idx < i1; idx += NTHR) cz[idx] = 0.f;
  }
  __syncthreads();
  const ushort* zg = p.zb + (size_t)b * Gg + 2 * Ll;
  for (int idx = i0 + tid; idx < i1; idx += NTHR) {
    int l = idx / Cc;
    float f  = sigf(bf2f(zg[idx]));
    float ii = sigf(bf2f(zg[Hh + idx]));
    float oo = sigf(bf2f(zg[2 * Hh + idx]));
    float ci = tanhfast(bf2f(zg[3 * Hh + idx]));
    float cl = p.cbuf[(size_t)b * Hh + idx];
    float fm = sfm[l], im = sim[l], ov = fm * im;
    float cn = ov * (f * cl + ii * ci) + (fm - ov) * cl + (im - ov) * ci;
    float hn = oo * tanhfast(cn);
    p.cbuf[(size_t)b * Hh + idx] = cn;
    p.hring[(size_t)slot_t * (Bsz * Hh) + (size_t)b * Hh + idx] = hn;
    p.A1[(size_t)b * A1LD + Ff + idx] = f2bf(hn);
    sh[idx] = hn;
  }
  if (half == 0 && t + 1 < Tt && tid < Ff)
    p.A1[(size_t)b * A1LD + tid] = f2bf(p.x[(size_t)b * (Tt * Ff) + (size_t)(t + 1) * Ff + tid]);
  __syncthreads();
  for (int idx = i0 + tid; idx < i1; idx += NTHR) {
    float a = 0.f;
    #pragma unroll
    for (int k = 0; k < Kw; ++k) {
      int slot = (t + 1 + k) % Kw;
      float hv = (k == Kw - 1) ? sh[idx]
                               : p.hring[(size_t)slot * (Bsz * Hh) + (size_t)b * Hh + idx];
      float v = hv * sld[k];
      p.Ab[(size_t)b * KC + (size_t)k * Hh + idx] = f2bf(v);
      a += v;
    }
    p.hmb[(size_t)b * Hh + idx] = f2bf(a * (1.f / Kw));
  }
}

// combine step tc: out[b][tc] = sigmoid( sum_o (theme2*conv + h)*ow + ob )
__device__ void combine_phase(const SP& p, int b0, int tc, float* misc) {
  const int tid = threadIdx.x;
  float* sred = misc;
  const int slot_t = tc % Kw;
  const float* cv = p.conv + (size_t)(tc & 1) * (Bsz * Hh);
  float d[4] = {0.f, 0.f, 0.f, 0.f};
  for (int o = tid; o < Hh; o += NTHR) {
    float oww = p.ow[o], cbv = p.cb[o];
    #pragma unroll
    for (int q = 0; q < 4; ++q) {
      int b = b0 + q;
      float c = cbv + cv[(size_t)b * Hh + o];
      float th = p.theme2[(size_t)b * Hh + o];
      float hv = p.hring[(size_t)slot_t * (Bsz * Hh) + (size_t)b * Hh + o];
      d[q] += (th * c + hv) * oww;
    }
  }
  #pragma unroll
  for (int q = 0; q < 4; ++q) {
    float v = d[q];
    for (int off = 32; off > 0; off >>= 1) v += __shfl_down(v, off);
    if ((tid & 63) == 0) sred[(tid >> 6) * 4 + q] = v;
  }
  __syncthreads();
  if (tid < 4) {
    float v = sred[tid] + sred[4 + tid] + sred[8 + tid] + sred[12 + tid];
    p.out[(size_t)(b0 + tid) * Tt + tc] = sigf(v + p.ob[0]);
  }
  __syncthreads();
}

// ---------------- phase dispatch ----------------
__device__ void p1_work(const SP& p, int t, int j, float* misc, ushort* lsA, ushort* lsB) {
  if (j < GATE_JOBS) gates_phase(p, j >> 1, j & 1, t, misc);
  else if (t > 0) theme2_job(p, j - GATE_JOBS, lsA, lsB);
}
__device__ void p2_work(const SP& p, int t, int j, float* misc, ushort* lsA, ushort* lsB) {
  if (j < G1_JOBS) { if (t + 1 < Tt) do_gemm1(p, j, lsA, lsB); }
  else if (j < G1_JOBS + TH1_JOBS) th1_job(p, j - G1_JOBS, lsA, lsB);
  else if (j < G1_JOBS + TH1_JOBS + CONV_JOBS) conv_job(p, j - G1_JOBS - TH1_JOBS, t, lsA, lsB);
  else if (t > 0) combine_phase(p, (j - G1_JOBS - TH1_JOBS - CONV_JOBS) * 4, t - 1, misc);
}

// ---------------- step kernels (stream-ordered) ----------------
__global__ void __launch_bounds__(NTHR, 3) k_p1(SP p, int t) {
  __shared__ ushort lsA[128 * 64];
  __shared__ ushort lsB[128 * 64];
  __shared__ float misc[Hh + 64];
  if (blockIdx.x < P1_JOBS) p1_work(p, t, blockIdx.x, misc, lsA, lsB);
}
__global__ void __launch_bounds__(NTHR, 3) k_p2(SP p, int t) {
  __shared__ ushort lsA[128 * 64];
  __shared__ ushort lsB[128 * 64];
  __shared__ float misc[Hh + 64];
  if (blockIdx.x < P2_JOBS) p2_work(p, t, blockIdx.x, misc, lsA, lsB);
}
__global__ void __launch_bounds__(NTHR, 3) k_pre(SP p) {
  __shared__ ushort lsA[128 * 64];
  __shared__ ushort lsB[128 * 64];
  do_gemm1(p, blockIdx.x, lsA, lsB);
}
__global__ void __launch_bounds__(NTHR, 3) k_tail1(SP p) {
  __shared__ ushort lsA[128 * 64];
  __shared__ ushort lsB[128 * 64];
  theme2_job(p, blockIdx.x, lsA, lsB);
}
__global__ void __launch_bounds__(NTHR, 3) k_tail2(SP p) {
  __shared__ float misc[Hh + 64];
  combine_phase(p, blockIdx.x * 4, Tt - 1, misc);
}

// ---------------- host entry ----------------
extern "C" void kernel_launch(void* const* d_in, const int* in_sizes, int n_in,
                              void* d_out, int out_size, void* d_ws, size_t ws_size,
                              hipStream_t stream) {
  (void)in_sizes; (void)n_in;
  SP p;
  p.x   = (const float*)d_in[0];
  p.kw  = (const float*)d_in[1];
  p.kb  = (const float*)d_in[2];
  p.rw  = (const float*)d_in[3];
  p.rb  = (const float*)d_in[4];
  p.sw  = (const float*)d_in[5];
  p.sb  = (const float*)d_in[6];
  p.rsw = (const float*)d_in[7];
  p.rsb = (const float*)d_in[8];
  p.cw  = (const float*)d_in[9];
  p.cb  = (const float*)d_in[10];
  p.ow  = (const float*)d_in[11];
  p.ob  = (const float*)d_in[12];
  float* ws = (float*)d_ws;
  p.zb = (ushort*)(ws + O_Z);
  p.zbias = ws + O_ZB; p.hring = ws + O_HR; p.cbuf = ws + O_CB;
  p.dring = ws + O_DR; p.theme2 = ws + O_T2; p.conv = ws + O_CV;
  ushort* wsb = (ushort*)(ws + O_BF);
  p.kwb = wsb + H_KWB; p.cwtb = wsb + H_CWT; p.swb = wsb + H_SWB; p.rswb = wsb + H_RSW;
  p.A1 = wsb + H_A1; p.Ab = wsb + H_AB; p.hmb = wsb + H_HM; p.th1b = wsb + H_T1B;
  p.out = (float*)d_out;

  if (ws_size < WS_FL * sizeof(float)) {
    k_fill<<<(out_size + NTHR - 1) / NTHR, NTHR, 0, stream>>>((float*)d_out, out_size, 0.5f);
    return;
  }

  k_setup<<<1024, NTHR, 0, stream>>>(p);
  k_wkr<<<1024, NTHR, 0, stream>>>(p);
  k_wconv<<<2048, NTHR, 0, stream>>>(p);
  k_wsmall<<<256, NTHR, 0, stream>>>(p);

  k_pre<<<G1_JOBS, NTHR, 0, stream>>>(p);                   // z(0)
  for (int t = 0; t < Tt; ++t) {
    k_p1<<<P1_JOBS, NTHR, 0, stream>>>(p, t);               // gates(t) || theme2(t-1)
    k_p2<<<P2_JOBS, NTHR, 0, stream>>>(p, t);               // z(t+1)+th1(t)+conv(t)+combine(t-1)
  }
  k_tail1<<<TH2_JOBS, NTHR, 0, stream>>>(p);                // theme2(399)
  k_tail2<<<COMB_JOBS, NTHR, 0, stream>>>(p);               // combine(399)
}